// Round 9
// baseline (1431.725 us; speedup 1.0000x reference)
//
#include <hip/hip_runtime.h>
#include <hip/hip_bf16.h>

#define Mdim 4096
#define Kdim 4096
#define Ndim 12288

typedef __attribute__((ext_vector_type(8))) short short8;
typedef __attribute__((ext_vector_type(4))) float floatx4;
typedef __attribute__((ext_vector_type(4))) int intx4;
typedef __attribute__((ext_vector_type(4))) unsigned short ushortx4;
typedef __attribute__((ext_vector_type(8))) unsigned short ushortx8;

static __device__ __forceinline__ unsigned short f2bf(float x) {
    __hip_bfloat16 h = __float2bfloat16(x);
    return __builtin_bit_cast(unsigned short, h);
}

// ---------------- Fused pre-pass: dequant+transpose AND xconv, ONE launch ----
// (R8 verbatim — measured at/near its ~66 us roofline; rest-slice is harness.)
#define DQ_BLOCKS 3072
#define XC_BLOCKS 2048

__global__ void __launch_bounds__(256)
prep(const int* __restrict__ Q, const float* __restrict__ S,
     const float* __restrict__ Z, unsigned short* __restrict__ Wt,
     const float* __restrict__ X, unsigned short* __restrict__ Xw)
{
    const int t = threadIdx.x;
    if (blockIdx.x < DQ_BLOCKS) {
        __shared__ unsigned short Ls[4][64][72];     // 36.9 KB
        const int b     = blockIdx.x;
        const int kbase = (b & 15) * 256;            // k-block 0..15
        const int n0    = (b >> 4) * 64;             // n-block 0..191
        const int tn = t & 15, tk = t >> 4;
        const int nc = tn * 4;

        floatx4 s4[4], z4[4];
        intx4 q[4][4];
        #pragma unroll
        for (int s = 0; s < 4; ++s) {
            const int k0 = kbase + s * 64;
            const int g  = k0 >> 6;                  // GROUP == 64
            s4[s] = *reinterpret_cast<const floatx4*>(&S[(size_t)g * Ndim + n0 + nc]);
            z4[s] = *reinterpret_cast<const floatx4*>(&Z[(size_t)g * Ndim + n0 + nc]);
            #pragma unroll
            for (int r = 0; r < 4; ++r)
                q[s][r] = *reinterpret_cast<const intx4*>(
                    &Q[(size_t)(k0 + tk * 4 + r) * Ndim + n0 + nc]);
        }
        #pragma unroll
        for (int s = 0; s < 4; ++s) {
            #pragma unroll
            for (int j = 0; j < 4; ++j) {
                const float sv = s4[s][j], zv = z4[s][j];
                ushortx4 w;
                w.x = f2bf(fmaf((float)q[s][0][j], sv, zv));
                w.y = f2bf(fmaf((float)q[s][1][j], sv, zv));
                w.z = f2bf(fmaf((float)q[s][2][j], sv, zv));
                w.w = f2bf(fmaf((float)q[s][3][j], sv, zv));
                *reinterpret_cast<ushortx4*>(&Ls[s][nc + j][tk * 4]) = w;
            }
        }
        __syncthreads();
        const int n_o = t >> 5;                      // 0..7
        const int ko  = (t & 31) * 8;                // 0..248
        const int so  = ko >> 6;                     // stage
        const int kc  = ko & 63;
        #pragma unroll
        for (int p = 0; p < 8; ++p) {
            const int n = n_o + p * 8;
            const ushortx8 v = *reinterpret_cast<const ushortx8*>(&Ls[so][n][kc]);
            *reinterpret_cast<ushortx8*>(
                &Wt[(size_t)(n0 + n) * Kdim + kbase + ko]) = v;
        }
    } else {
        const int xb = blockIdx.x - DQ_BLOCKS;       // 0..2047
        const size_t stride = (size_t)XC_BLOCKS * 256 * 8;
        size_t base = ((size_t)xb * 256 + t) * 8;
        floatx4 a[4], b2[4];
        #pragma unroll
        for (int it = 0; it < 4; ++it) {
            a[it]  = *reinterpret_cast<const floatx4*>(&X[base + it * stride]);
            b2[it] = *reinterpret_cast<const floatx4*>(&X[base + it * stride + 4]);
        }
        #pragma unroll
        for (int it = 0; it < 4; ++it) {
            ushortx8 w;
            w[0] = f2bf(a[it].x); w[1] = f2bf(a[it].y);
            w[2] = f2bf(a[it].z); w[3] = f2bf(a[it].w);
            w[4] = f2bf(b2[it].x); w[5] = f2bf(b2[it].y);
            w[6] = f2bf(b2[it].z); w[7] = f2bf(b2[it].w);
            *reinterpret_cast<ushortx8*>(&Xw[base + it * stride]) = w;
        }
    }
}

// ---------------- Main GEMM v2: NO-LDS direct-from-cache ---------------------
// Cycle ledger of the LDS version (417 us = 5212 cyc/tile/CU): MFMA 620,
// LDS reads ~2304, LDS-DMA writes ~512, rest = 8-barrier/tile convoy skew.
// Three correct schedules (R1/R2/R6) all hit 420-450 -> the LDS machinery IS
// the floor. Both operands are fragment-contiguous in memory (A-frag = 16 B
// of Xw[m][k], B-frag = 16 B of Wt[n][k]) and L3-resident (Xw 32 MB, Wt
// 100 MB; ~25 MB B-slice per XCD under the swizzle ~= L2-sized). So: load
// fragments directly from cache. Zero barriers, zero waitcnt asm, zero
// swizzle; waves independent; compiler pipelines register loads.
// Per 32-k step: 12 x global_load_dwordx4 (16 rows x 64 B lines per instr)
// + 16 independent MFMA. Redundancy (A x4 waves, B x2) absorbed by L1/L2;
// worst-case aggregate L2 demand ~27 TB/s < 34 TB/s ceiling.
__global__ void __launch_bounds__(512, 2)
gemm_nolds(const unsigned short* __restrict__ A, const unsigned short* __restrict__ B,
           const float* __restrict__ bias, float* __restrict__ O)
{
    // XCD-aware bijective swizzle (768 % 8 == 0), then 8-row-band grouping
    const int nblk = Ndim / 256;                 // 48
    const int cpx  = (Mdim / 256) * nblk / 8;    // 96 blocks per XCD
    const int bid  = blockIdx.x;
    const int swz  = (bid & 7) * cpx + (bid >> 3);
    const int gsz  = 8 * nblk;                   // 384
    const int grp  = swz / gsz;
    const int r    = swz % gsz;
    const int m0   = (grp * 8 + (r & 7)) * 256;
    const int n0   = (r >> 3) * 256;

    const int t    = threadIdx.x;
    const int wave = t >> 6;                     // 0..7
    const int lane = t & 63;
    const int wm   = (wave >> 2) * 128;          // 128-row half
    const int wn   = (wave & 3) * 64;            // 64-col quarter
    const int lrow = lane & 15;
    const int quad = lane >> 4;

    // lane's fragment base rows; frag k-window = k0 + quad*8 (16 B contiguous)
    const unsigned short* Ab = A + (size_t)(m0 + wm + lrow) * Kdim + quad * 8;
    const unsigned short* Bb = B + (size_t)(n0 + wn + lrow) * Kdim + quad * 8;

    floatx4 acc[8][4];
    #pragma unroll
    for (int i = 0; i < 8; ++i)
        #pragma unroll
        for (int j = 0; j < 4; ++j)
            acc[i][j] = floatx4{0.f, 0.f, 0.f, 0.f};

    #pragma unroll 2
    for (int k0 = 0; k0 < Kdim; k0 += 32) {
        short8 af[8], bf[4];
        #pragma unroll
        for (int i = 0; i < 8; ++i)
            af[i] = *reinterpret_cast<const short8*>(&Ab[(size_t)i * 16 * Kdim + k0]);
        #pragma unroll
        for (int j = 0; j < 4; ++j)
            bf[j] = *reinterpret_cast<const short8*>(&Bb[(size_t)j * 16 * Kdim + k0]);
        #pragma unroll
        for (int i = 0; i < 8; ++i)
            #pragma unroll
            for (int j = 0; j < 4; ++j)
                acc[i][j] = __builtin_amdgcn_mfma_f32_16x16x32_bf16(
                    af[i], bf[j], acc[i][j], 0, 0, 0);
    }

    // -------- epilogue (unchanged) --------
    #pragma unroll
    for (int j = 0; j < 4; ++j) {
        const int col = n0 + wn + j * 16 + lrow;
        const float bv = bias[col];
        #pragma unroll
        for (int i = 0; i < 8; ++i) {
            const int rbase = m0 + wm + i * 16 + quad * 4;
            #pragma unroll
            for (int rr = 0; rr < 4; ++rr)
                O[(size_t)(rbase + rr) * Ndim + col] = acc[i][j][rr] + bv;
        }
    }
}

// ---------------- Fallback (fused, ws-independent) ---------------------------
__global__ void __launch_bounds__(256)
w2a16_gemm_fb(const float* __restrict__ X, const int* __restrict__ Q,
              const float* __restrict__ S, const float* __restrict__ Z,
              const float* __restrict__ bias, float* __restrict__ O)
{
    __shared__ unsigned short Asf[128][72];
    __shared__ unsigned short Bsf[128][72];
    const int t  = threadIdx.x;
    const int n0 = blockIdx.x * 128;
    const int m0 = blockIdx.y * 128;
    const int wave = t >> 6, lane = t & 63;
    const int wm = (wave & 1) * 64, wn = (wave >> 1) * 64;
    const int lrow = lane & 15, quad = lane >> 4;
    floatx4 acc[4][4];
    #pragma unroll
    for (int i = 0; i < 4; ++i)
        #pragma unroll
        for (int j = 0; j < 4; ++j) acc[i][j] = floatx4{0.f, 0.f, 0.f, 0.f};
    const int a_row0 = t >> 4, a_c = (t & 15) * 4;
    const int b_n = t & 127, b_k0 = (t >> 7) * 32;
    for (int k0 = 0; k0 < Kdim; k0 += 64) {
        #pragma unroll
        for (int i = 0; i < 8; ++i) {
            const int row = a_row0 + i * 16;
            const floatx4 v = *reinterpret_cast<const floatx4*>(
                &X[(size_t)(m0 + row) * Kdim + k0 + a_c]);
            ushortx4 w;
            w.x = f2bf(v.x); w.y = f2bf(v.y); w.z = f2bf(v.z); w.w = f2bf(v.w);
            *reinterpret_cast<ushortx4*>(&Asf[row][a_c]) = w;
        }
        const int g = k0 >> 6;
        const float s = S[(size_t)g * Ndim + n0 + b_n];
        const float z = Z[(size_t)g * Ndim + n0 + b_n];
        #pragma unroll
        for (int i = 0; i < 8; ++i) {
            const int kk = b_k0 + i * 4;
            const int* qp = &Q[(size_t)(k0 + kk) * Ndim + n0 + b_n];
            ushortx4 w;
            w.x = f2bf(fmaf((float)qp[0],                s, z));
            w.y = f2bf(fmaf((float)qp[(size_t)Ndim],     s, z));
            w.z = f2bf(fmaf((float)qp[(size_t)2 * Ndim], s, z));
            w.w = f2bf(fmaf((float)qp[(size_t)3 * Ndim], s, z));
            *reinterpret_cast<ushortx4*>(&Bsf[b_n][kk]) = w;
        }
        __syncthreads();
        #pragma unroll
        for (int kk = 0; kk < 64; kk += 32) {
            short8 afv[4], bfv[4];
            #pragma unroll
            for (int i = 0; i < 4; ++i)
                afv[i] = *reinterpret_cast<const short8*>(&Asf[wm + i * 16 + lrow][kk + quad * 8]);
            #pragma unroll
            for (int j = 0; j < 4; ++j)
                bfv[j] = *reinterpret_cast<const short8*>(&Bsf[wn + j * 16 + lrow][kk + quad * 8]);
            #pragma unroll
            for (int i = 0; i < 4; ++i)
                #pragma unroll
                for (int j = 0; j < 4; ++j)
                    acc[i][j] = __builtin_amdgcn_mfma_f32_16x16x32_bf16(afv[i], bfv[j], acc[i][j], 0, 0, 0);
        }
        __syncthreads();
    }
    #pragma unroll
    for (int j = 0; j < 4; ++j) {
        const int col = n0 + wn + j * 16 + lrow;
        const float bv = bias[col];
        #pragma unroll
        for (int i = 0; i < 4; ++i) {
            const int rbase = m0 + wm + i * 16 + quad * 4;
            #pragma unroll
            for (int rr = 0; rr < 4; ++rr)
                O[(size_t)(rbase + rr) * Ndim + col] = acc[i][j][rr] + bv;
        }
    }
}

extern "C" void kernel_launch(void* const* d_in, const int* in_sizes, int n_in,
                              void* d_out, int out_size, void* d_ws, size_t ws_size,
                              hipStream_t stream) {
    const float* X  = (const float*)d_in[0];
    const int*   Q  = (const int*)d_in[1];
    const float* S  = (const float*)d_in[2];
    const float* Z  = (const float*)d_in[3];
    const float* Bi = (const float*)d_in[4];
    float* O = (float*)d_out;

    const size_t wt_bytes = (size_t)Kdim * Ndim * 2;
    const size_t xw_bytes = (size_t)Mdim * Kdim * 2;

    if (ws_size >= wt_bytes + xw_bytes) {
        unsigned short* Wt = (unsigned short*)d_ws;
        unsigned short* Xw = (unsigned short*)((char*)d_ws + wt_bytes);

        hipLaunchKernelGGL(prep, dim3(DQ_BLOCKS + XC_BLOCKS), dim3(256), 0, stream,
                           Q, S, Z, Wt, X, Xw);

        const int nblocks = (Mdim / 256) * (Ndim / 256);  // 768
        hipLaunchKernelGGL(gemm_nolds, dim3(nblocks), dim3(512), 0, stream, Xw, Wt, Bi, O);
    } else {
        dim3 grid(Ndim / 128, Mdim / 128);
        hipLaunchKernelGGL(w2a16_gemm_fb, grid, dim3(256), 0, stream, X, Q, S, Z, Bi, O);
    }
}